// Round 1
// baseline (1282.398 us; speedup 1.0000x reference)
//
#include <hip/hip_runtime.h>
#include <stdint.h>

// Problem constants
#define NROWS 131072   // 32768*2048/512 rows of the block-reshaped X
#define NCOLS 512      // BLOCK
#define MROWS 32768    // N
#define DDIM  2048     // D_IN = D_OUT
#define EPSV  1e-5f

typedef __attribute__((ext_vector_type(8))) short bf16x8;
typedef __attribute__((ext_vector_type(4))) float f32x4;

__device__ __forceinline__ short f2bf(float f) {
  uint32_t u = __float_as_uint(f);
  u += 0x7fffu + ((u >> 16) & 1u);   // RNE
  return (short)(u >> 16);
}
__device__ __forceinline__ float bf2f(short s) {
  return __uint_as_float(((uint32_t)(uint16_t)s) << 16);
}
__device__ __forceinline__ uint32_t pk2(short a, short b) {
  return (uint32_t)(uint16_t)a | ((uint32_t)(uint16_t)b << 16);
}
// async global->LDS, 16B per lane; LDS dest must be wave-uniform base (+lane*16 implicit)
__device__ __forceinline__ void gload_lds16(const void* g, void* l) {
  __builtin_amdgcn_global_load_lds((const __attribute__((address_space(1))) void*)g,
                                   (__attribute__((address_space(3))) void*)l, 16, 0, 0);
}

// ---------------------------------------------------------------------------
// 1) x fp32 -> xbf bf16 (row-major, same linear layout serves both the
//    [32768][2048] and [131072][512] views) + column sums of the 512-view.
//    grid 512 x 256 threads; block covers 256 rows of the 512-view.
// ---------------------------------------------------------------------------
__global__ __launch_bounds__(256) void convert_colsum_kernel(const float* __restrict__ x,
                                                             short* __restrict__ xbf,
                                                             float* __restrict__ colsum) {
  const int t = threadIdx.x;
  const int half = t >> 7;          // 0/1: which of 2 rows per iteration
  const int c4 = t & 127;           // columns 4*c4 .. 4*c4+3
  const size_t r0 = (size_t)blockIdx.x * 256;
  float s0 = 0.f, s1 = 0.f, s2 = 0.f, s3 = 0.f;
  for (int it = 0; it < 128; ++it) {
    const size_t r = r0 + (size_t)it * 2 + half;
    const float4 v = *(const float4*)&x[r * NCOLS + c4 * 4];
    s0 += v.x; s1 += v.y; s2 += v.z; s3 += v.w;
    *(uint2*)&xbf[r * NCOLS + c4 * 4] =
        make_uint2(pk2(f2bf(v.x), f2bf(v.y)), pk2(f2bf(v.z), f2bf(v.w)));
  }
  __shared__ float red[128][4];
  if (half) { red[c4][0] = s0; red[c4][1] = s1; red[c4][2] = s2; red[c4][3] = s3; }
  __syncthreads();
  if (!half) {
    s0 += red[c4][0]; s1 += red[c4][1]; s2 += red[c4][2]; s3 += red[c4][3];
    atomicAdd(&colsum[c4 * 4 + 0], s0);
    atomicAdd(&colsum[c4 * 4 + 1], s1);
    atomicAdd(&colsum[c4 * 4 + 2], s2);
    atomicAdd(&colsum[c4 * 4 + 3], s3);
  }
}

// ---------------------------------------------------------------------------
// 2) xbf [131072][512] -> xt [512][131072] (bf16 transpose, register-only).
//    Per wave: 64 cols x 64 rows. 8x8 in-register butterfly transpose across
//    stride-8 lane groups (__shfl_xor 8/16/32). Each lane ends with 128 B
//    (64 r-values) of ONE column -> granule-clean coalesced writes.
//    grid 4096 x 256 (4 waves/block; 16384 wave-tiles = 8 ct x 2048 rt).
// ---------------------------------------------------------------------------
__global__ __launch_bounds__(256) void transpose_kernel(const short* __restrict__ xbf,
                                                        short* __restrict__ xt) {
  const int lane = threadIdx.x & 63;
  const int wv   = threadIdx.x >> 6;
  const int idx  = blockIdx.x * 4 + wv;
  const int ct   = idx & 7;          // column tile (64 cols)
  const int rt   = idx >> 3;         // row tile (64 rows)
  const int g    = lane >> 3;        // in-group index 0..7
  const int c8   = lane & 7;         // which 8-col chunk
  const int c0   = ct * 64;
  const size_t r0 = (size_t)rt * 64;
  const size_t cl = (size_t)(c0 + c8 * 8 + g);   // this lane's output column
  uint32_t uo[32];
#pragma unroll
  for (int i = 0; i < 8; ++i) {
    const uint4 v = *(const uint4*)&xbf[(r0 + i * 8 + g) * NCOLS + c0 + c8 * 8];
    uint32_t u0 = v.x, u1 = v.y, u2 = v.z, u3 = v.w;
    {  // stage 0: elem bit0 <-> lane bit3
      uint32_t p0 = __shfl_xor(u0, 8), p1 = __shfl_xor(u1, 8),
               p2 = __shfl_xor(u2, 8), p3 = __shfl_xor(u3, 8);
      if (lane & 8) {
        u0 = (p0 >> 16) | (u0 & 0xffff0000u);
        u1 = (p1 >> 16) | (u1 & 0xffff0000u);
        u2 = (p2 >> 16) | (u2 & 0xffff0000u);
        u3 = (p3 >> 16) | (u3 & 0xffff0000u);
      } else {
        u0 = (u0 & 0xffffu) | (p0 << 16);
        u1 = (u1 & 0xffffu) | (p1 << 16);
        u2 = (u2 & 0xffffu) | (p2 << 16);
        u3 = (u3 & 0xffffu) | (p3 << 16);
      }
    }
    {  // stage 1: elem bit1 <-> lane bit4
      uint32_t p0 = __shfl_xor(u0, 16), p1 = __shfl_xor(u1, 16),
               p2 = __shfl_xor(u2, 16), p3 = __shfl_xor(u3, 16);
      if (lane & 16) { u0 = p1; u2 = p3; } else { u1 = p0; u3 = p2; }
    }
    {  // stage 2: elem bit2 <-> lane bit5
      uint32_t p0 = __shfl_xor(u0, 32), p1 = __shfl_xor(u1, 32),
               p2 = __shfl_xor(u2, 32), p3 = __shfl_xor(u3, 32);
      if (lane & 32) { u0 = p2; u1 = p3; } else { u2 = p0; u3 = p1; }
    }
    uo[i * 4 + 0] = u0; uo[i * 4 + 1] = u1; uo[i * 4 + 2] = u2; uo[i * 4 + 3] = u3;
  }
#pragma unroll
  for (int i = 0; i < 8; ++i)
    *(uint4*)&xt[cl * NROWS + r0 + i * 8] =
        make_uint4(uo[i * 4 + 0], uo[i * 4 + 1], uo[i * 4 + 2], uo[i * 4 + 3]);
}

// ---------------------------------------------------------------------------
// 3) S = X^T X from xt (m97 structure: global_load_lds w=16, linear LDS,
//    128x128 tile, BK=32, bf16 MFMA). grid (10 tile-pairs, 64 K-chunks).
// ---------------------------------------------------------------------------
__global__ __launch_bounds__(256) void syrk_xt_kernel(const short* __restrict__ xt,
                                                      float* __restrict__ S) {
  const int TI[10] = {0,0,0,0,1,1,1,2,2,3};
  const int TJ[10] = {0,1,2,3,1,2,3,2,3,3};
  const int I = TI[blockIdx.x], J = TJ[blockIdx.x];
  const int baseA = I * 128, baseB = J * 128;
  const size_t k0 = (size_t)blockIdx.y * 2048;

  __shared__ short As[128 * 32];  // As[c][kk] linear, c = xt row
  __shared__ short Bs[128 * 32];

  const int tid = threadIdx.x;
  const int lane = tid & 63, wave = tid >> 6;
  const int wm = wave >> 1, wn = wave & 1;
  const int quad = lane >> 4, l16 = lane & 15;

  f32x4 acc[4][4];
#pragma unroll
  for (int a = 0; a < 4; ++a)
#pragma unroll
    for (int b = 0; b < 4; ++b)
#pragma unroll
      for (int r = 0; r < 4; ++r) acc[a][b][r] = 0.f;

  for (int ks = 0; ks < 2048; ks += 32) {
#pragma unroll
    for (int j = 0; j < 2; ++j) {
      const int q = wave * 2 + j;            // wave-uniform
      const int ci = q * 64 + lane;          // chunk 0..511
      const int row = ci >> 2, ko = (ci & 3) * 8;
      gload_lds16(&xt[(size_t)(baseA + row) * NROWS + k0 + ks + ko], &As[q * 512]);
      gload_lds16(&xt[(size_t)(baseB + row) * NROWS + k0 + ks + ko], &Bs[q * 512]);
    }
    __syncthreads();
    bf16x8 af[4], bfr[4];
#pragma unroll
    for (int tm = 0; tm < 4; ++tm)
      af[tm] = *(const bf16x8*)&As[(wm * 64 + tm * 16 + l16) * 32 + quad * 8];
#pragma unroll
    for (int tn = 0; tn < 4; ++tn)
      bfr[tn] = *(const bf16x8*)&Bs[(wn * 64 + tn * 16 + l16) * 32 + quad * 8];
#pragma unroll
    for (int tm = 0; tm < 4; ++tm)
#pragma unroll
      for (int tn = 0; tn < 4; ++tn)
        acc[tm][tn] = __builtin_amdgcn_mfma_f32_16x16x32_bf16(af[tm], bfr[tn], acc[tm][tn], 0, 0, 0);
    __syncthreads();
  }
#pragma unroll
  for (int tm = 0; tm < 4; ++tm)
#pragma unroll
    for (int tn = 0; tn < 4; ++tn)
#pragma unroll
      for (int r = 0; r < 4; ++r) {
        int i = baseA + wm * 64 + tm * 16 + quad * 4 + r;
        int j = baseB + wn * 64 + tn * 16 + l16;
        atomicAdd(&S[i * NCOLS + j], acc[tm][tn][r]);
      }
}

// ---------------------------------------------------------------------------
// Legacy fallback (ws too small): original verified kernels
// ---------------------------------------------------------------------------
__global__ __launch_bounds__(512) void colsum_kernel(const float* __restrict__ x,
                                                     float* __restrict__ colsum) {
  const int t = threadIdx.x;
  const size_t r0 = (size_t)blockIdx.x * 256;
  float s[8] = {0.f,0.f,0.f,0.f,0.f,0.f,0.f,0.f};
  for (int r = 0; r < 256; r += 8) {
#pragma unroll
    for (int u = 0; u < 8; ++u) s[u] += x[(r0 + r + u) * NCOLS + t];
  }
  float tot = ((s[0]+s[1])+(s[2]+s[3])) + ((s[4]+s[5])+(s[6]+s[7]));
  atomicAdd(&colsum[t], tot);
}

__global__ __launch_bounds__(256) void syrk_f32_kernel(const float* __restrict__ x,
                                                       float* __restrict__ S) {
  const int TI[10] = {0,0,0,0,1,1,1,2,2,3};
  const int TJ[10] = {0,1,2,3,1,2,3,2,3,3};
  const int I = TI[blockIdx.x], J = TJ[blockIdx.x];
  const int baseA = I * 128, baseB = J * 128;
  const size_t k0 = (size_t)blockIdx.y * 2048;

  __shared__ short As[128][40];
  __shared__ short Bs[128][40];

  const int tid = threadIdx.x;
  const int lane = tid & 63, wave = tid >> 6;
  const int wm = wave >> 1, wn = wave & 1;
  const int quad = lane >> 4, l16 = lane & 15;

  f32x4 acc[4][4];
#pragma unroll
  for (int a = 0; a < 4; ++a)
#pragma unroll
    for (int b = 0; b < 4; ++b)
#pragma unroll
      for (int r = 0; r < 4; ++r) acc[a][b][r] = 0.f;

  for (int ks = 0; ks < 2048; ks += 32) {
#pragma unroll
    for (int i = 0; i < 4; ++i) {
      int idx = tid + i * 256;
      int kk = idx >> 5, c4 = idx & 31;
      size_t row = k0 + ks + kk;
      float4 va = *(const float4*)&x[row * NCOLS + baseA + c4 * 4];
      As[c4*4+0][kk] = f2bf(va.x);
      As[c4*4+1][kk] = f2bf(va.y);
      As[c4*4+2][kk] = f2bf(va.z);
      As[c4*4+3][kk] = f2bf(va.w);
      float4 vb = *(const float4*)&x[row * NCOLS + baseB + c4 * 4];
      Bs[c4*4+0][kk] = f2bf(vb.x);
      Bs[c4*4+1][kk] = f2bf(vb.y);
      Bs[c4*4+2][kk] = f2bf(vb.z);
      Bs[c4*4+3][kk] = f2bf(vb.w);
    }
    __syncthreads();
    bf16x8 af[4], bfr[4];
#pragma unroll
    for (int tm = 0; tm < 4; ++tm)
      af[tm] = *(const bf16x8*)&As[wm*64 + tm*16 + l16][quad * 8];
#pragma unroll
    for (int tn = 0; tn < 4; ++tn)
      bfr[tn] = *(const bf16x8*)&Bs[wn*64 + tn*16 + l16][quad * 8];
#pragma unroll
    for (int tm = 0; tm < 4; ++tm)
#pragma unroll
      for (int tn = 0; tn < 4; ++tn)
        acc[tm][tn] = __builtin_amdgcn_mfma_f32_16x16x32_bf16(af[tm], bfr[tn], acc[tm][tn], 0, 0, 0);
    __syncthreads();
  }
#pragma unroll
  for (int tm = 0; tm < 4; ++tm)
#pragma unroll
    for (int tn = 0; tn < 4; ++tn)
#pragma unroll
      for (int r = 0; r < 4; ++r) {
        int i = baseA + wm*64 + tm*16 + quad*4 + r;
        int j = baseB + wn*64 + tn*16 + l16;
        atomicAdd(&S[i * NCOLS + j], acc[tm][tn][r]);
      }
}

// ---------------------------------------------------------------------------
// 4) mean, cov finalize (+ Frobenius norm^2), Y/Z init
// ---------------------------------------------------------------------------
__global__ void mean_kernel(const float* __restrict__ colsum, float* __restrict__ mean) {
  int i = blockIdx.x * 256 + threadIdx.x;
  if (i < NCOLS) mean[i] = colsum[i] * (1.0f / (float)NROWS);
}

__global__ __launch_bounds__(256) void finalize_cov_kernel(const float* __restrict__ S,
                                                           const float* __restrict__ mean,
                                                           float* __restrict__ cov,
                                                           float* __restrict__ norm2) {
  const int i = blockIdx.x;
  const float mi = mean[i];
  float local = 0.f;
  for (int j = threadIdx.x; j < NCOLS; j += 256) {
    float s = ((i >> 7) > (j >> 7)) ? S[j * NCOLS + i] : S[i * NCOLS + j];
    float c = s * (1.0f / (float)NROWS) - mi * mean[j];
    if (i == j) c += EPSV;
    cov[i * NCOLS + j] = c;
    local += c * c;
  }
  __shared__ float red[256];
  red[threadIdx.x] = local;
  __syncthreads();
  for (int s = 128; s > 0; s >>= 1) {
    if (threadIdx.x < s) red[threadIdx.x] += red[threadIdx.x + s];
    __syncthreads();
  }
  if (threadIdx.x == 0) atomicAdd(norm2, red[0]);
}

__global__ void init_yz_kernel(const float* __restrict__ cov, const float* __restrict__ norm2,
                               float* __restrict__ Y, float* __restrict__ Z) {
  int idx = blockIdx.x * 256 + threadIdx.x;
  float rn = rsqrtf(*norm2);
  Y[idx] = cov[idx] * rn;
  int i = idx >> 9, j = idx & 511;
  Z[idx] = (i == j) ? 1.f : 0.f;
}

// ---------------------------------------------------------------------------
// 5) split-bf16 (hi/lo, 3-MFMA) emulated-fp32 GEMM for the small matrices.
//    A [M][512], B [512][512] fp32 row-major. 64x64 tile, 4 waves (2x2),
//    per-wave 32x32 (2x2 fragments 16x16x32). Error ~2^-16 rel ~ fp32-class.
//    MODE 0: C = A@B (fp32)   MODE 1: C = 1.5I - 0.5*(A@B) (fp32)
//    MODE 2: C = bf16((A@B) * norm2^{-1/4})
// ---------------------------------------------------------------------------
template <int MODE>
__device__ __forceinline__ void mgemm512(const float* __restrict__ A,
                                         const float* __restrict__ B,
                                         void* __restrict__ Cp,
                                         const float* __restrict__ norm2,
                                         int m0, int n0) {
  __shared__ short Ah[64 * 40], Al[64 * 40];   // [row][kk], stride 40
  __shared__ short Bh[64 * 40], Bl[64 * 40];   // [col][kk], stride 40
  const int tid = threadIdx.x;
  const int lane = tid & 63, wave = tid >> 6;
  const int wm = wave >> 1, wn = wave & 1;
  const int quad = lane >> 4, l16 = lane & 15;

  f32x4 acc[2][2];
#pragma unroll
  for (int a = 0; a < 2; ++a)
#pragma unroll
    for (int b = 0; b < 2; ++b)
#pragma unroll
      for (int r = 0; r < 4; ++r) acc[a][b][r] = 0.f;

  for (int k0 = 0; k0 < 512; k0 += 32) {
#pragma unroll
    for (int i = 0; i < 2; ++i) {
      const int idx = tid + i * 256;         // 0..511
      {  // A tile: 64 rows x 32 k, vectorized hi/lo stores
        const int row = idx >> 3, q = idx & 7;
        const float4 v = *(const float4*)&A[(size_t)(m0 + row) * 512 + k0 + q * 4];
        const short h0 = f2bf(v.x), h1 = f2bf(v.y), h2 = f2bf(v.z), h3 = f2bf(v.w);
        const short e0 = f2bf(v.x - bf2f(h0)), e1 = f2bf(v.y - bf2f(h1));
        const short e2 = f2bf(v.z - bf2f(h2)), e3 = f2bf(v.w - bf2f(h3));
        *(uint2*)&Ah[row * 40 + q * 4] = make_uint2(pk2(h0, h1), pk2(h2, h3));
        *(uint2*)&Al[row * 40 + q * 4] = make_uint2(pk2(e0, e1), pk2(e2, e3));
      }
      {  // B tile: 32 k x 64 n, transposed scatter (tiny, conflicts OK)
        const int kk = idx >> 4, c4 = idx & 15;
        const float4 v = *(const float4*)&B[(size_t)(k0 + kk) * 512 + n0 + c4 * 4];
        const short h0 = f2bf(v.x), h1 = f2bf(v.y), h2 = f2bf(v.z), h3 = f2bf(v.w);
        Bh[(c4 * 4 + 0) * 40 + kk] = h0;
        Bh[(c4 * 4 + 1) * 40 + kk] = h1;
        Bh[(c4 * 4 + 2) * 40 + kk] = h2;
        Bh[(c4 * 4 + 3) * 40 + kk] = h3;
        Bl[(c4 * 4 + 0) * 40 + kk] = f2bf(v.x - bf2f(h0));
        Bl[(c4 * 4 + 1) * 40 + kk] = f2bf(v.y - bf2f(h1));
        Bl[(c4 * 4 + 2) * 40 + kk] = f2bf(v.z - bf2f(h2));
        Bl[(c4 * 4 + 3) * 40 + kk] = f2bf(v.w - bf2f(h3));
      }
    }
    __syncthreads();
    bf16x8 ah[2], al[2], bh[2], bl[2];
#pragma unroll
    for (int t = 0; t < 2; ++t) {
      ah[t] = *(const bf16x8*)&Ah[(wm * 32 + t * 16 + l16) * 40 + quad * 8];
      al[t] = *(const bf16x8*)&Al[(wm * 32 + t * 16 + l16) * 40 + quad * 8];
      bh[t] = *(const bf16x8*)&Bh[(wn * 32 + t * 16 + l16) * 40 + quad * 8];
      bl[t] = *(const bf16x8*)&Bl[(wn * 32 + t * 16 + l16) * 40 + quad * 8];
    }
#pragma unroll
    for (int tm = 0; tm < 2; ++tm)
#pragma unroll
      for (int tn = 0; tn < 2; ++tn) {
        acc[tm][tn] = __builtin_amdgcn_mfma_f32_16x16x32_bf16(al[tm], bh[tn], acc[tm][tn], 0, 0, 0);
        acc[tm][tn] = __builtin_amdgcn_mfma_f32_16x16x32_bf16(ah[tm], bl[tn], acc[tm][tn], 0, 0, 0);
        acc[tm][tn] = __builtin_amdgcn_mfma_f32_16x16x32_bf16(ah[tm], bh[tn], acc[tm][tn], 0, 0, 0);
      }
    __syncthreads();
  }
  float s = 1.f;
  if (MODE == 2) s = rsqrtf(sqrtf(*norm2));
#pragma unroll
  for (int tm = 0; tm < 2; ++tm)
#pragma unroll
    for (int tn = 0; tn < 2; ++tn)
#pragma unroll
      for (int r = 0; r < 4; ++r) {
        const int rr = m0 + wm * 32 + tm * 16 + quad * 4 + r;
        const int cc = n0 + wn * 32 + tn * 16 + l16;
        float v = acc[tm][tn][r];
        if (MODE == 1) v = (rr == cc ? 1.5f : 0.f) - 0.5f * v;
        if (MODE == 2) ((short*)Cp)[(size_t)rr * 512 + cc] = f2bf(v * s);
        else           ((float*)Cp)[(size_t)rr * 512 + cc] = v;
      }
}

__global__ __launch_bounds__(256) void mgemm_T_kernel(const float* __restrict__ Z,
                                                      const float* __restrict__ Y,
                                                      float* __restrict__ T) {
  mgemm512<1>(Z, Y, T, nullptr, blockIdx.y * 64, blockIdx.x * 64);
}

__global__ __launch_bounds__(256) void mgemm_pair_kernel(const float* __restrict__ A0, const float* __restrict__ B0, float* __restrict__ C0,
                                                         const float* __restrict__ A1, const float* __restrict__ B1, float* __restrict__ C1) {
  const float* A = blockIdx.z ? A1 : A0;
  const float* B = blockIdx.z ? B1 : B0;
  float* C = blockIdx.z ? C1 : C0;
  mgemm512<0>(A, B, C, nullptr, blockIdx.y * 64, blockIdx.x * 64);
}

__global__ __launch_bounds__(256) void mwgemm_kernel(const float* __restrict__ Wt,
                                                     const float* __restrict__ Zf,
                                                     const float* __restrict__ norm2,
                                                     short* __restrict__ wbf) {
  mgemm512<2>(Wt, Zf, (void*)wbf, norm2, blockIdx.y * 64, blockIdx.x * 64);
}

// ---------------------------------------------------------------------------
// 6) b[o] = bias[o] - sum_k wfull[o][k] * mean[k % 512]
// ---------------------------------------------------------------------------
__global__ __launch_bounds__(256) void bvec_kernel(const short* __restrict__ wbf,
                                                   const float* __restrict__ mean,
                                                   const float* __restrict__ bias,
                                                   float* __restrict__ bvec) {
  const int o = blockIdx.x;
  float p = 0.f;
  for (int k = threadIdx.x; k < DDIM; k += 256)
    p += bf2f(wbf[(size_t)o * DDIM + k]) * mean[k & 511];
  __shared__ float red[256];
  red[threadIdx.x] = p;
  __syncthreads();
  for (int s = 128; s > 0; s >>= 1) {
    if (threadIdx.x < s) red[threadIdx.x] += red[threadIdx.x + s];
    __syncthreads();
  }
  if (threadIdx.x == 0) bvec[o] = bias[o] - red[0];
}

// ---------------------------------------------------------------------------
// 7a) out = x @ w^T + b, m97 structure: both operands bf16 in global,
//     global_load_lds width=16, linear LDS [128][32], 16 MFMA / K-step.
// ---------------------------------------------------------------------------
__global__ __launch_bounds__(256) void final_gemm_bf_kernel(const short* __restrict__ xbf,
                                                            const short* __restrict__ wbf,
                                                            const float* __restrict__ bvec,
                                                            float* __restrict__ out) {
  __shared__ short Xs[128 * 32];
  __shared__ short Ws[128 * 32];
  const int n0 = blockIdx.x * 128, m0 = blockIdx.y * 128;
  const int tid = threadIdx.x;
  const int lane = tid & 63, wave = tid >> 6;
  const int wm = wave >> 1, wn = wave & 1;
  const int quad = lane >> 4, l16 = lane & 15;

  f32x4 acc[4][4];
#pragma unroll
  for (int a = 0; a < 4; ++a)
#pragma unroll
    for (int b = 0; b < 4; ++b)
#pragma unroll
      for (int r = 0; r < 4; ++r) acc[a][b][r] = 0.f;

  for (int kt = 0; kt < DDIM; kt += 32) {
#pragma unroll
    for (int j = 0; j < 2; ++j) {
      const int q = wave * 2 + j;
      const int ci = q * 64 + lane;
      const int row = ci >> 2, ko = (ci & 3) * 8;
      gload_lds16(&xbf[(size_t)(m0 + row) * DDIM + kt + ko], &Xs[q * 512]);
      gload_lds16(&wbf[(size_t)(n0 + row) * DDIM + kt + ko], &Ws[q * 512]);
    }
    __syncthreads();
    bf16x8 af[4], bfr[4];
#pragma unroll
    for (int tm = 0; tm < 4; ++tm)
      af[tm] = *(const bf16x8*)&Xs[(wm * 64 + tm * 16 + l16) * 32 + quad * 8];
#pragma unroll
    for (int tn = 0; tn < 4; ++tn)
      bfr[tn] = *(const bf16x8*)&Ws[(wn * 64 + tn * 16 + l16) * 32 + quad * 8];
#pragma unroll
    for (int tm = 0; tm < 4; ++tm)
#pragma unroll
      for (int tn = 0; tn < 4; ++tn)
        acc[tm][tn] = __builtin_amdgcn_mfma_f32_16x16x32_bf16(af[tm], bfr[tn], acc[tm][tn], 0, 0, 0);
    __syncthreads();
  }
  float bv[4];
#pragma unroll
  for (int tn = 0; tn < 4; ++tn) bv[tn] = bvec[n0 + wn * 64 + tn * 16 + l16];
#pragma unroll
  for (int tm = 0; tm < 4; ++tm)
#pragma unroll
    for (int tn = 0; tn < 4; ++tn)
#pragma unroll
      for (int r = 0; r < 4; ++r) {
        size_t row = (size_t)(m0 + wm * 64 + tm * 16 + quad * 4 + r);
        int col = n0 + wn * 64 + tn * 16 + l16;
        out[row * DDIM + col] = acc[tm][tn][r] + bv[tn];
      }
}

// 7b) legacy fallback final gemm (fp32 x, convert in staging)
__global__ __launch_bounds__(256) void final_gemm_f32_kernel(const float* __restrict__ x,
                                                             const short* __restrict__ wbf,
                                                             const float* __restrict__ bvec,
                                                             float* __restrict__ out) {
  __shared__ short Xs[128][40];
  __shared__ short Ws[128][40];
  const int n0 = blockIdx.x * 128, m0 = blockIdx.y * 128;
  const int tid = threadIdx.x;
  const int lane = tid & 63, wave = tid >> 6;
  const int wm = wave >> 1, wn = wave & 1;
  const int quad = lane >> 4, l16 = lane & 15;

  f32x4 acc[4][4];
#pragma unroll
  for (int a = 0; a < 4; ++a)
#pragma unroll
    for (int b = 0; b < 4; ++b)
#pragma unroll
      for (int r = 0; r < 4; ++r) acc[a][b][r] = 0.f;

  for (int kt = 0; kt < DDIM; kt += 32) {
#pragma unroll
    for (int i = 0; i < 4; ++i) {
      int idx = tid + i * 256;
      int row = idx >> 3, c4 = idx & 7;
      float4 v = *(const float4*)&x[(size_t)(m0 + row) * DDIM + kt + c4 * 4];
      *(uint2*)&Xs[row][c4 * 4] = make_uint2(pk2(f2bf(v.x), f2bf(v.y)), pk2(f2bf(v.z), f2bf(v.w)));
    }
#pragma unroll
    for (int i = 0; i < 2; ++i) {
      int idx = tid + i * 256;
      int row = idx >> 2, c8 = idx & 3;
      int4 v = *(const int4*)&wbf[(size_t)(n0 + row) * DDIM + kt + c8 * 8];
      *(int4*)&Ws[row][c8 * 8] = v;
    }
    __syncthreads();
    bf16x8 af[4], bfr[4];
#pragma unroll
    for (int tm = 0; tm < 4; ++tm)
      af[tm] = *(const bf16x8*)&Xs[wm*64 + tm*16 + l16][quad * 8];
#pragma unroll
    for (int tn = 0; tn < 4; ++tn)
      bfr[tn] = *(const bf16x8*)&Ws[wn*64 + tn*16 + l16][quad * 8];
#pragma unroll
    for (int tm = 0; tm < 4; ++tm)
#pragma unroll
      for (int tn = 0; tn < 4; ++tn)
        acc[tm][tn] = __builtin_amdgcn_mfma_f32_16x16x32_bf16(af[tm], bfr[tn], acc[tm][tn], 0, 0, 0);
    __syncthreads();
  }
  float bv[4];
#pragma unroll
  for (int tn = 0; tn < 4; ++tn) bv[tn] = bvec[n0 + wn*64 + tn*16 + l16];
#pragma unroll
  for (int tm = 0; tm < 4; ++tm)
#pragma unroll
    for (int tn = 0; tn < 4; ++tn)
#pragma unroll
      for (int r = 0; r < 4; ++r) {
        size_t row = (size_t)(m0 + wm*64 + tm*16 + quad*4 + r);
        int col = n0 + wn*64 + tn*16 + l16;
        out[row * DDIM + col] = acc[tm][tn][r] + bv[tn];
      }
}

// ---------------------------------------------------------------------------
extern "C" void kernel_launch(void* const* d_in, const int* in_sizes, int n_in,
                              void* d_out, int out_size, void* d_ws, size_t ws_size,
                              hipStream_t stream) {
  const float* x      = (const float*)d_in[0];   // 32768*2048
  const float* weight = (const float*)d_in[1];   // 2048*2048
  const float* bias   = (const float*)d_in[2];   // 2048
  float* out = (float*)d_out;
  char* ws = (char*)d_ws;

  float* colsum = (float*)(ws + 0);
  float* mean   = (float*)(ws + 4096);
  float* norm2  = (float*)(ws + 8192);
  float* bvec   = (float*)(ws + 12288);
  float* Sbuf   = (float*)(ws + (1u << 20));
  float* covb   = (float*)(ws + (2u << 20));
  float* Ybuf   = (float*)(ws + (3u << 20));
  float* Zbuf   = (float*)(ws + (4u << 20));
  float* Tbuf   = (float*)(ws + (5u << 20));
  float* Y2buf  = (float*)(ws + (6u << 20));
  float* Z2buf  = (float*)(ws + (7u << 20));
  short* wbf    = (short*)(ws + (8u << 20));     // 8 MB -> 16 MB small region
  short* xbf    = (short*)(ws + (16u << 20));    // 128 MB bf16 copy of x
  short* xt     = (short*)d_out;                  // 128 MB X^T scratch (dead before final gemm)

  // fast path needs 16 MB small region + 128 MB xbf
  const bool fast = ws_size >= (size_t)(16u << 20) + (size_t)MROWS * DDIM * 2;

  hipMemsetAsync(colsum, 0, 512 * 4, stream);
  hipMemsetAsync(norm2, 0, 4, stream);
  hipMemsetAsync(Sbuf, 0, 512 * 512 * 4, stream);

  if (fast) {
    convert_colsum_kernel<<<512, 256, 0, stream>>>(x, xbf, colsum);
    transpose_kernel<<<4096, 256, 0, stream>>>(xbf, xt);
    syrk_xt_kernel<<<dim3(10, 64), 256, 0, stream>>>(xt, Sbuf);
  } else {
    colsum_kernel<<<512, 512, 0, stream>>>(x, colsum);
    syrk_f32_kernel<<<dim3(10, 64), 256, 0, stream>>>(x, Sbuf);
  }
  mean_kernel<<<2, 256, 0, stream>>>(colsum, mean);
  finalize_cov_kernel<<<512, 256, 0, stream>>>(Sbuf, mean, covb, norm2);
  init_yz_kernel<<<1024, 256, 0, stream>>>(covb, norm2, Ybuf, Zbuf);

  float* Y = Ybuf; float* Z = Zbuf; float* Y2 = Y2buf; float* Z2 = Z2buf;
  for (int it = 0; it < 5; ++it) {
    mgemm_T_kernel<<<dim3(8, 8), 256, 0, stream>>>(Z, Y, Tbuf);
    mgemm_pair_kernel<<<dim3(8, 8, 2), 256, 0, stream>>>(Y, Tbuf, Y2, Tbuf, Z, Z2);
    float* t;
    t = Y; Y = Y2; Y2 = t;
    t = Z; Z = Z2; Z2 = t;
  }

  mwgemm_kernel<<<dim3(8, 128), 256, 0, stream>>>(weight, Z, norm2, wbf);
  bvec_kernel<<<2048, 256, 0, stream>>>(wbf, mean, bias, bvec);
  if (fast)
    final_gemm_bf_kernel<<<dim3(16, 256), 256, 0, stream>>>(xbf, wbf, bvec, out);
  else
    final_gemm_f32_kernel<<<dim3(16, 256), 256, 0, stream>>>(x, wbf, bvec, out);
}